// Round 4
// baseline (148.928 us; speedup 1.0000x reference)
//
#include <hip/hip_runtime.h>

#define N_NODES 10000
#define N_EDGES 640000
#define DIM 128
#define GEMM_ROWS 16

// ---------------------------------------------------------------------------
// 0) zero deg[] ourselves: hipMemsetAsync became a 43 us fillBuffer dispatch
//    inside the graph (blit/SDMA handoff overhead). A plain kernel is ~2 us.
// ---------------------------------------------------------------------------
__global__ void zero_deg_kernel(int* __restrict__ deg) {
    const int i = blockIdx.x * blockDim.x + threadIdx.x;
    if (i < N_NODES) deg[i] = 0;
}

// ---------------------------------------------------------------------------
// 1) degree over dst (self-loop accounted as +1 in dinv). int4 = 4 edges/thread.
//    Counting atomics have no used return value -> non-returning atomic, cheap.
// ---------------------------------------------------------------------------
__global__ void deg_kernel(const int* __restrict__ dst, int* __restrict__ deg) {
    const int t = blockIdx.x * blockDim.x + threadIdx.x;
    if (t < N_EDGES / 4) {
        const int4 d4 = reinterpret_cast<const int4*>(dst)[t];
        atomicAdd(&deg[d4.x], 1);
        atomicAdd(&deg[d4.y], 1);
        atomicAdd(&deg[d4.z], 1);
        atomicAdd(&deg[d4.w], 1);
    }
}

// ---------------------------------------------------------------------------
// 2) exclusive scan of deg -> row_ptr + fill cursor + dinv, single block,
//    16 waves, shuffle-based (3 barriers per 1024-chunk).
// ---------------------------------------------------------------------------
__global__ void __launch_bounds__(1024)
scan_kernel(const int* __restrict__ deg,
            float* __restrict__ dinv,
            int* __restrict__ row_ptr,
            int* __restrict__ fill) {
    __shared__ int wsum[16];
    __shared__ int chunk_total;
    const int tid = threadIdx.x;
    const int lane = tid & 63;
    const int wid = tid >> 6;
    int offset = 0;
    for (int base = 0; base < N_NODES; base += 1024) {
        const int idx = base + tid;
        const int v = (idx < N_NODES) ? deg[idx] : 0;
        // intra-wave inclusive scan
        int sc = v;
#pragma unroll
        for (int s = 1; s < 64; s <<= 1) {
            const int t = __shfl_up(sc, s, 64);
            if (lane >= s) sc += t;
        }
        if (lane == 63) wsum[wid] = sc;
        __syncthreads();
        if (wid == 0) {
            const int w = (lane < 16) ? wsum[lane] : 0;
            int ws = w;
#pragma unroll
            for (int s = 1; s < 16; s <<= 1) {
                const int t = __shfl_up(ws, s, 64);
                if (lane >= s) ws += t;
            }
            if (lane == 15) chunk_total = ws;
            if (lane < 16) wsum[lane] = ws - w;  // exclusive wave offset
        }
        __syncthreads();
        const int excl = sc - v + wsum[wid] + offset;
        if (idx < N_NODES) {
            row_ptr[idx] = excl;
            fill[idx] = excl;
            dinv[idx] = rsqrtf((float)(v + 1));  // +1 = self-loop
        }
        offset += chunk_total;
        __syncthreads();  // protect wsum/chunk_total before next chunk
    }
    if (tid == 0) row_ptr[N_NODES] = offset;  // == N_EDGES
}

// ---------------------------------------------------------------------------
// 3) xws = (x @ W) * dinv[row]   — 16-row tile in LDS, 16x register reuse of W
// ---------------------------------------------------------------------------
__global__ void gemm_xw_kernel(const float* __restrict__ x,
                               const float* __restrict__ W,
                               const float* __restrict__ dinv,
                               float* __restrict__ xws) {
    __shared__ float xs[GEMM_ROWS][DIM];
    const int c = threadIdx.x;          // 0..127 (output column)
    const int r0 = blockIdx.x * GEMM_ROWS;
#pragma unroll
    for (int i = 0; i < GEMM_ROWS; ++i)
        xs[i][c] = x[(r0 + i) * DIM + c];
    __syncthreads();

    float acc[GEMM_ROWS];
#pragma unroll
    for (int i = 0; i < GEMM_ROWS; ++i) acc[i] = 0.f;

    for (int k = 0; k < DIM; ++k) {
        const float w = W[k * DIM + c];
#pragma unroll
        for (int i = 0; i < GEMM_ROWS; ++i)
            acc[i] = fmaf(xs[i][k], w, acc[i]);   // xs[i][k]: LDS broadcast
    }
#pragma unroll
    for (int i = 0; i < GEMM_ROWS; ++i)
        xws[(r0 + i) * DIM + c] = acc[i] * dinv[r0 + i];
}

// ---------------------------------------------------------------------------
// 4) counting-sort edges by dst. 1 edge/thread: atomicAdd RETURNS a value
//    (~600-900ns L2 round trip) -> need max waves in flight to hide it.
//    (4 edges/thread regressed to 42us: 625 blocks was too little TLP.)
// ---------------------------------------------------------------------------
__global__ void csr_fill_kernel(const int* __restrict__ src,
                                const int* __restrict__ dst,
                                int* __restrict__ fill,
                                int* __restrict__ ssrc) {
    const int e = blockIdx.x * blockDim.x + threadIdx.x;
    if (e < N_EDGES) {
        const int d = dst[e];
        const int pos = atomicAdd(&fill[d], 1);
        ssrc[pos] = src[e];
    }
}

// ---------------------------------------------------------------------------
// 5) aggregate: one wave per node. out[v] = relu((sum xws[s] + xws[v])*dinv[v] + b)
//    Lane owns 2 dims (float2 -> 512 B coalesced row read); ssrc reads are
//    wave-uniform -> scalar loads.
// ---------------------------------------------------------------------------
__global__ void __launch_bounds__(64)
aggregate_kernel(const int* __restrict__ row_ptr,
                 const int* __restrict__ ssrc,
                 const float* __restrict__ xws,
                 const float* __restrict__ dinv,
                 const float* __restrict__ b,
                 float* __restrict__ out) {
    const int v = blockIdx.x;
    const int c2 = threadIdx.x * 2;
    const int beg = row_ptr[v];
    const int end = row_ptr[v + 1];

    float ax = 0.f, ay = 0.f;
    int j = beg;
    for (; j + 3 < end; j += 4) {
        const int s0 = ssrc[j], s1 = ssrc[j + 1], s2 = ssrc[j + 2], s3 = ssrc[j + 3];
        const float2 v0 = *reinterpret_cast<const float2*>(&xws[s0 * DIM + c2]);
        const float2 v1 = *reinterpret_cast<const float2*>(&xws[s1 * DIM + c2]);
        const float2 v2 = *reinterpret_cast<const float2*>(&xws[s2 * DIM + c2]);
        const float2 v3 = *reinterpret_cast<const float2*>(&xws[s3 * DIM + c2]);
        ax += v0.x + v1.x + v2.x + v3.x;
        ay += v0.y + v1.y + v2.y + v3.y;
    }
    for (; j < end; ++j) {
        const int s = ssrc[j];
        const float2 vv = *reinterpret_cast<const float2*>(&xws[s * DIM + c2]);
        ax += vv.x;
        ay += vv.y;
    }
    // self-loop term: xws[v] already scaled by dinv[v]
    const float2 xv = *reinterpret_cast<const float2*>(&xws[v * DIM + c2]);
    ax += xv.x;
    ay += xv.y;

    const float dv = dinv[v];
    const float2 bb = *reinterpret_cast<const float2*>(&b[c2]);
    float2 o;
    o.x = fmaxf(fmaf(ax, dv, bb.x), 0.f);
    o.y = fmaxf(fmaf(ay, dv, bb.y), 0.f);
    *reinterpret_cast<float2*>(&out[v * DIM + c2]) = o;
}

extern "C" void kernel_launch(void* const* d_in, const int* in_sizes, int n_in,
                              void* d_out, int out_size, void* d_ws, size_t ws_size,
                              hipStream_t stream) {
    const float* x  = (const float*)d_in[0];
    const int*   ei = (const int*)d_in[1];   // [2, E] int32
    const float* W  = (const float*)d_in[2];
    const float* b  = (const float*)d_in[3];
    float* out = (float*)d_out;

    // workspace layout (16 B aligned chunks)
    float* xws     = (float*)d_ws;                    // N*DIM floats  (5.12 MB)
    int*   deg     = (int*)(xws + N_NODES * DIM);     // 10016 ints
    float* dinv    = (float*)(deg + 10016);           // 10016 floats
    int*   row_ptr = (int*)(dinv + 10016);            // 10016 ints (incl. [N])
    int*   fill    = row_ptr + 10016;                 // 10016 ints
    int*   ssrc    = fill + 10016;                    // E ints (2.56 MB)

    const int* src = ei;
    const int* dst = ei + N_EDGES;

    zero_deg_kernel<<<(N_NODES + 255) / 256, 256, 0, stream>>>(deg);
    deg_kernel<<<(N_EDGES / 4 + 255) / 256, 256, 0, stream>>>(dst, deg);
    scan_kernel<<<1, 1024, 0, stream>>>(deg, dinv, row_ptr, fill);
    gemm_xw_kernel<<<N_NODES / GEMM_ROWS, DIM, 0, stream>>>(x, W, dinv, xws);
    csr_fill_kernel<<<(N_EDGES + 255) / 256, 256, 0, stream>>>(src, dst, fill, ssrc);
    aggregate_kernel<<<N_NODES, 64, 0, stream>>>(row_ptr, ssrc, xws, dinv, b, out);
}

// Round 5
// 130.243 us; speedup vs baseline: 1.1435x; 1.1435x over previous
//
#include <hip/hip_runtime.h>

#define N_NODES 10000
#define N_EDGES 640000
#define DIM 128
#define GEMM_ROWS 16
#define PAD 16   // one counter per 64B cache line: TCC serializes RMW per line

// ---------------------------------------------------------------------------
// 0) zero padded deg[] (640 KB). hipMemsetAsync = 43us fillBuffer dispatch in
//    graph; plain kernel ~2us.
// ---------------------------------------------------------------------------
__global__ void zero_deg_kernel(int* __restrict__ deg) {
    const int i = blockIdx.x * blockDim.x + threadIdx.x;
    if (i < N_NODES * PAD) deg[i] = 0;
}

// ---------------------------------------------------------------------------
// 1) degree over dst, padded counters (16x more L2-line parallelism for RMW).
// ---------------------------------------------------------------------------
__global__ void deg_kernel(const int* __restrict__ dst, int* __restrict__ deg) {
    const int t = blockIdx.x * blockDim.x + threadIdx.x;
    if (t < N_EDGES / 4) {
        const int4 d4 = reinterpret_cast<const int4*>(dst)[t];
        atomicAdd(&deg[d4.x * PAD], 1);
        atomicAdd(&deg[d4.y * PAD], 1);
        atomicAdd(&deg[d4.z * PAD], 1);
        atomicAdd(&deg[d4.w * PAD], 1);
    }
}

// ---------------------------------------------------------------------------
// 2) exclusive scan of padded deg -> dense row_ptr + padded fill + dinv.
//    Single block, 16 waves, shuffle-based.
// ---------------------------------------------------------------------------
__global__ void __launch_bounds__(1024)
scan_kernel(const int* __restrict__ deg,
            float* __restrict__ dinv,
            int* __restrict__ row_ptr,
            int* __restrict__ fill) {
    __shared__ int wsum[16];
    __shared__ int chunk_total;
    const int tid = threadIdx.x;
    const int lane = tid & 63;
    const int wid = tid >> 6;
    int offset = 0;
    for (int base = 0; base < N_NODES; base += 1024) {
        const int idx = base + tid;
        const int v = (idx < N_NODES) ? deg[idx * PAD] : 0;
        // intra-wave inclusive scan
        int sc = v;
#pragma unroll
        for (int s = 1; s < 64; s <<= 1) {
            const int t = __shfl_up(sc, s, 64);
            if (lane >= s) sc += t;
        }
        if (lane == 63) wsum[wid] = sc;
        __syncthreads();
        if (wid == 0) {
            const int w = (lane < 16) ? wsum[lane] : 0;
            int ws = w;
#pragma unroll
            for (int s = 1; s < 16; s <<= 1) {
                const int t = __shfl_up(ws, s, 64);
                if (lane >= s) ws += t;
            }
            if (lane == 15) chunk_total = ws;
            if (lane < 16) wsum[lane] = ws - w;  // exclusive wave offset
        }
        __syncthreads();
        const int excl = sc - v + wsum[wid] + offset;
        if (idx < N_NODES) {
            row_ptr[idx] = excl;
            fill[idx * PAD] = excl;
            dinv[idx] = rsqrtf((float)(v + 1));  // +1 = self-loop
        }
        offset += chunk_total;
        __syncthreads();  // protect wsum/chunk_total before next chunk
    }
    if (tid == 0) row_ptr[N_NODES] = offset;  // == N_EDGES
}

// ---------------------------------------------------------------------------
// 3) xws = (x @ W) * dinv[row]   — 16-row tile in LDS, 16x register reuse of W
// ---------------------------------------------------------------------------
__global__ void gemm_xw_kernel(const float* __restrict__ x,
                               const float* __restrict__ W,
                               const float* __restrict__ dinv,
                               float* __restrict__ xws) {
    __shared__ float xs[GEMM_ROWS][DIM];
    const int c = threadIdx.x;          // 0..127 (output column)
    const int r0 = blockIdx.x * GEMM_ROWS;
#pragma unroll
    for (int i = 0; i < GEMM_ROWS; ++i)
        xs[i][c] = x[(r0 + i) * DIM + c];
    __syncthreads();

    float acc[GEMM_ROWS];
#pragma unroll
    for (int i = 0; i < GEMM_ROWS; ++i) acc[i] = 0.f;

    for (int k = 0; k < DIM; ++k) {
        const float w = W[k * DIM + c];
#pragma unroll
        for (int i = 0; i < GEMM_ROWS; ++i)
            acc[i] = fmaf(xs[i][k], w, acc[i]);   // xs[i][k]: LDS broadcast
    }
#pragma unroll
    for (int i = 0; i < GEMM_ROWS; ++i)
        xws[(r0 + i) * DIM + c] = acc[i] * dinv[r0 + i];
}

// ---------------------------------------------------------------------------
// 4) counting-sort edges by dst, padded cursors. 4 edges/thread: 4 independent
//    returning atomics in flight per thread.
// ---------------------------------------------------------------------------
__global__ void csr_fill_kernel(const int* __restrict__ src,
                                const int* __restrict__ dst,
                                int* __restrict__ fill,
                                int* __restrict__ ssrc) {
    const int t = blockIdx.x * blockDim.x + threadIdx.x;
    if (t < N_EDGES / 4) {
        const int4 s4 = reinterpret_cast<const int4*>(src)[t];
        const int4 d4 = reinterpret_cast<const int4*>(dst)[t];
        const int p0 = atomicAdd(&fill[d4.x * PAD], 1);
        const int p1 = atomicAdd(&fill[d4.y * PAD], 1);
        const int p2 = atomicAdd(&fill[d4.z * PAD], 1);
        const int p3 = atomicAdd(&fill[d4.w * PAD], 1);
        ssrc[p0] = s4.x;
        ssrc[p1] = s4.y;
        ssrc[p2] = s4.z;
        ssrc[p3] = s4.w;
    }
}

// ---------------------------------------------------------------------------
// 5) aggregate: one wave per node. out[v] = relu((sum xws[s] + xws[v])*dinv[v] + b)
//    Lane owns 2 dims (float2 -> 512 B coalesced row read); 8 rows unrolled
//    for 8 gathers in flight.
// ---------------------------------------------------------------------------
__global__ void __launch_bounds__(64)
aggregate_kernel(const int* __restrict__ row_ptr,
                 const int* __restrict__ ssrc,
                 const float* __restrict__ xws,
                 const float* __restrict__ dinv,
                 const float* __restrict__ b,
                 float* __restrict__ out) {
    const int v = blockIdx.x;
    const int c2 = threadIdx.x * 2;
    const int beg = row_ptr[v];
    const int end = row_ptr[v + 1];

    float ax = 0.f, ay = 0.f;
    int j = beg;
    for (; j + 7 < end; j += 8) {
        int s[8];
#pragma unroll
        for (int u = 0; u < 8; ++u) s[u] = ssrc[j + u];
        float2 r[8];
#pragma unroll
        for (int u = 0; u < 8; ++u)
            r[u] = *reinterpret_cast<const float2*>(&xws[s[u] * DIM + c2]);
#pragma unroll
        for (int u = 0; u < 8; ++u) {
            ax += r[u].x;
            ay += r[u].y;
        }
    }
    for (; j < end; ++j) {
        const int s = ssrc[j];
        const float2 vv = *reinterpret_cast<const float2*>(&xws[s * DIM + c2]);
        ax += vv.x;
        ay += vv.y;
    }
    // self-loop term: xws[v] already scaled by dinv[v]
    const float2 xv = *reinterpret_cast<const float2*>(&xws[v * DIM + c2]);
    ax += xv.x;
    ay += xv.y;

    const float dv = dinv[v];
    const float2 bb = *reinterpret_cast<const float2*>(&b[c2]);
    float2 o;
    o.x = fmaxf(fmaf(ax, dv, bb.x), 0.f);
    o.y = fmaxf(fmaf(ay, dv, bb.y), 0.f);
    *reinterpret_cast<float2*>(&out[v * DIM + c2]) = o;
}

extern "C" void kernel_launch(void* const* d_in, const int* in_sizes, int n_in,
                              void* d_out, int out_size, void* d_ws, size_t ws_size,
                              hipStream_t stream) {
    const float* x  = (const float*)d_in[0];
    const int*   ei = (const int*)d_in[1];   // [2, E] int32
    const float* W  = (const float*)d_in[2];
    const float* b  = (const float*)d_in[3];
    float* out = (float*)d_out;

    // workspace layout (16 B aligned chunks)
    float* xws     = (float*)d_ws;                    // N*DIM floats  (5.12 MB)
    int*   deg     = (int*)(xws + N_NODES * DIM);     // N*PAD ints (640 KB, padded)
    int*   fill    = deg + N_NODES * PAD;             // N*PAD ints (640 KB, padded)
    float* dinv    = (float*)(fill + N_NODES * PAD);  // 10016 floats
    int*   row_ptr = (int*)(dinv + 10016);            // 10016 ints (incl. [N])
    int*   ssrc    = row_ptr + 10016;                 // E ints (2.56 MB)

    const int* src = ei;
    const int* dst = ei + N_EDGES;

    zero_deg_kernel<<<(N_NODES * PAD + 255) / 256, 256, 0, stream>>>(deg);
    deg_kernel<<<(N_EDGES / 4 + 255) / 256, 256, 0, stream>>>(dst, deg);
    scan_kernel<<<1, 1024, 0, stream>>>(deg, dinv, row_ptr, fill);
    gemm_xw_kernel<<<N_NODES / GEMM_ROWS, DIM, 0, stream>>>(x, W, dinv, xws);
    csr_fill_kernel<<<(N_EDGES / 4 + 255) / 256, 256, 0, stream>>>(src, dst, fill, ssrc);
    aggregate_kernel<<<N_NODES, 64, 0, stream>>>(row_ptr, ssrc, xws, dinv, b, out);
}

// Round 6
// 92.302 us; speedup vs baseline: 1.6135x; 1.4111x over previous
//
#include <hip/hip_runtime.h>
#include <hip/hip_fp16.h>

#define N_NODES 10000
#define N_EDGES 640000
#define DIM 128
#define GEMM_ROWS 16
#define PAD 16   // one counter per 64B cache line: TCC serializes RMW per line

// ---------------------------------------------------------------------------
// 0) zero padded deg[] (640 KB). hipMemsetAsync = 43us fillBuffer dispatch in
//    graph; plain kernel ~2us.
// ---------------------------------------------------------------------------
__global__ void zero_deg_kernel(int* __restrict__ deg) {
    const int i = blockIdx.x * blockDim.x + threadIdx.x;
    if (i < N_NODES * PAD) deg[i] = 0;
}

// ---------------------------------------------------------------------------
// 1) degree over dst AND per-edge rank in one pass: the atomic's return value
//    IS the edge's slot within its destination bucket. Padded counters.
// ---------------------------------------------------------------------------
__global__ void deg_rank_kernel(const int* __restrict__ dst,
                                int* __restrict__ deg,
                                int* __restrict__ rank) {
    const int t = blockIdx.x * blockDim.x + threadIdx.x;
    if (t < N_EDGES / 4) {
        const int4 d4 = reinterpret_cast<const int4*>(dst)[t];
        int4 r4;
        r4.x = atomicAdd(&deg[d4.x * PAD], 1);
        r4.y = atomicAdd(&deg[d4.y * PAD], 1);
        r4.z = atomicAdd(&deg[d4.z * PAD], 1);
        r4.w = atomicAdd(&deg[d4.w * PAD], 1);
        reinterpret_cast<int4*>(rank)[t] = r4;
    }
}

// ---------------------------------------------------------------------------
// 2) exclusive scan of padded deg -> dense row_ptr + dinv. Single block,
//    16 waves, shuffle-based.
// ---------------------------------------------------------------------------
__global__ void __launch_bounds__(1024)
scan_kernel(const int* __restrict__ deg,
            float* __restrict__ dinv,
            int* __restrict__ row_ptr) {
    __shared__ int wsum[16];
    __shared__ int chunk_total;
    const int tid = threadIdx.x;
    const int lane = tid & 63;
    const int wid = tid >> 6;
    int offset = 0;
    for (int base = 0; base < N_NODES; base += 1024) {
        const int idx = base + tid;
        const int v = (idx < N_NODES) ? deg[idx * PAD] : 0;
        // intra-wave inclusive scan
        int sc = v;
#pragma unroll
        for (int s = 1; s < 64; s <<= 1) {
            const int t = __shfl_up(sc, s, 64);
            if (lane >= s) sc += t;
        }
        if (lane == 63) wsum[wid] = sc;
        __syncthreads();
        if (wid == 0) {
            const int w = (lane < 16) ? wsum[lane] : 0;
            int ws = w;
#pragma unroll
            for (int s = 1; s < 16; s <<= 1) {
                const int t = __shfl_up(ws, s, 64);
                if (lane >= s) ws += t;
            }
            if (lane == 15) chunk_total = ws;
            if (lane < 16) wsum[lane] = ws - w;  // exclusive wave offset
        }
        __syncthreads();
        const int excl = sc - v + wsum[wid] + offset;
        if (idx < N_NODES) {
            row_ptr[idx] = excl;
            dinv[idx] = rsqrtf((float)(v + 1));  // +1 = self-loop
        }
        offset += chunk_total;
        __syncthreads();  // protect wsum/chunk_total before next chunk
    }
    if (tid == 0) row_ptr[N_NODES] = offset;  // == N_EDGES
}

// ---------------------------------------------------------------------------
// 3) xwh = half((x @ W) * dinv[row]) — 16-row tile in LDS, 16x register reuse
//    of W. fp16 halves the aggregate gather traffic; error ~6e-5 << 1.4e-2.
// ---------------------------------------------------------------------------
__global__ void gemm_xw_kernel(const float* __restrict__ x,
                               const float* __restrict__ W,
                               const float* __restrict__ dinv,
                               __half* __restrict__ xwh) {
    __shared__ float xs[GEMM_ROWS][DIM];
    const int c = threadIdx.x;          // 0..127 (output column)
    const int r0 = blockIdx.x * GEMM_ROWS;
#pragma unroll
    for (int i = 0; i < GEMM_ROWS; ++i)
        xs[i][c] = x[(r0 + i) * DIM + c];
    __syncthreads();

    float acc[GEMM_ROWS];
#pragma unroll
    for (int i = 0; i < GEMM_ROWS; ++i) acc[i] = 0.f;

    for (int k = 0; k < DIM; ++k) {
        const float w = W[k * DIM + c];
#pragma unroll
        for (int i = 0; i < GEMM_ROWS; ++i)
            acc[i] = fmaf(xs[i][k], w, acc[i]);   // xs[i][k]: LDS broadcast
    }
#pragma unroll
    for (int i = 0; i < GEMM_ROWS; ++i)
        xwh[(r0 + i) * DIM + c] = __float2half(acc[i] * dinv[r0 + i]);
}

// ---------------------------------------------------------------------------
// 4) counting-sort scatter, NO atomics: pos = row_ptr[dst] + rank.
// ---------------------------------------------------------------------------
__global__ void csr_fill_kernel(const int* __restrict__ src,
                                const int* __restrict__ dst,
                                const int* __restrict__ rank,
                                const int* __restrict__ row_ptr,
                                int* __restrict__ ssrc) {
    const int t = blockIdx.x * blockDim.x + threadIdx.x;
    if (t < N_EDGES / 4) {
        const int4 s4 = reinterpret_cast<const int4*>(src)[t];
        const int4 d4 = reinterpret_cast<const int4*>(dst)[t];
        const int4 r4 = reinterpret_cast<const int4*>(rank)[t];
        ssrc[row_ptr[d4.x] + r4.x] = s4.x;
        ssrc[row_ptr[d4.y] + r4.y] = s4.y;
        ssrc[row_ptr[d4.z] + r4.z] = s4.z;
        ssrc[row_ptr[d4.w] + r4.w] = s4.w;
    }
}

// ---------------------------------------------------------------------------
// 5) aggregate: one wave per node, fp16 gathers (half2/lane = 256 B per row),
//    fp32 accumulate. out[v] = relu((sum xwh[s] + xwh[v])*dinv[v] + b)
// ---------------------------------------------------------------------------
__global__ void __launch_bounds__(64)
aggregate_kernel(const int* __restrict__ row_ptr,
                 const int* __restrict__ ssrc,
                 const __half2* __restrict__ xwh,   // [N][DIM/2]
                 const float* __restrict__ dinv,
                 const float* __restrict__ b,
                 float* __restrict__ out) {
    const int v = blockIdx.x;
    const int c = threadIdx.x;          // half2 index: dims 2c, 2c+1
    const int beg = row_ptr[v];
    const int end = row_ptr[v + 1];

    float ax = 0.f, ay = 0.f;
    int j = beg;
    for (; j + 7 < end; j += 8) {
        int s[8];
#pragma unroll
        for (int u = 0; u < 8; ++u) s[u] = ssrc[j + u];
        __half2 r[8];
#pragma unroll
        for (int u = 0; u < 8; ++u) r[u] = xwh[s[u] * (DIM / 2) + c];
#pragma unroll
        for (int u = 0; u < 8; ++u) {
            const float2 f = __half22float2(r[u]);
            ax += f.x;
            ay += f.y;
        }
    }
    for (; j < end; ++j) {
        const float2 f = __half22float2(xwh[ssrc[j] * (DIM / 2) + c]);
        ax += f.x;
        ay += f.y;
    }
    // self-loop term: xwh[v] already scaled by dinv[v]
    const float2 xv = __half22float2(xwh[v * (DIM / 2) + c]);
    ax += xv.x;
    ay += xv.y;

    const float dv = dinv[v];
    const float2 bb = *reinterpret_cast<const float2*>(&b[2 * c]);
    float2 o;
    o.x = fmaxf(fmaf(ax, dv, bb.x), 0.f);
    o.y = fmaxf(fmaf(ay, dv, bb.y), 0.f);
    *reinterpret_cast<float2*>(&out[v * DIM + 2 * c]) = o;
}

extern "C" void kernel_launch(void* const* d_in, const int* in_sizes, int n_in,
                              void* d_out, int out_size, void* d_ws, size_t ws_size,
                              hipStream_t stream) {
    const float* x  = (const float*)d_in[0];
    const int*   ei = (const int*)d_in[1];   // [2, E] int32
    const float* W  = (const float*)d_in[2];
    const float* b  = (const float*)d_in[3];
    float* out = (float*)d_out;

    // workspace layout (16 B aligned chunks)
    __half* xwh    = (__half*)d_ws;                   // N*DIM halves (2.56 MB)
    int*   deg     = (int*)(xwh + N_NODES * DIM);     // N*PAD ints (640 KB, padded)
    float* dinv    = (float*)(deg + N_NODES * PAD);   // 10016 floats
    int*   row_ptr = (int*)(dinv + 10016);            // 10016 ints (incl. [N])
    int*   rank    = row_ptr + 10016;                 // E ints (2.56 MB)
    int*   ssrc    = rank + N_EDGES;                  // E ints (2.56 MB)

    const int* src = ei;
    const int* dst = ei + N_EDGES;

    zero_deg_kernel<<<(N_NODES * PAD + 255) / 256, 256, 0, stream>>>(deg);
    deg_rank_kernel<<<(N_EDGES / 4 + 255) / 256, 256, 0, stream>>>(dst, deg, rank);
    scan_kernel<<<1, 1024, 0, stream>>>(deg, dinv, row_ptr);
    gemm_xw_kernel<<<N_NODES / GEMM_ROWS, DIM, 0, stream>>>(x, W, dinv, xwh);
    csr_fill_kernel<<<(N_EDGES / 4 + 255) / 256, 256, 0, stream>>>(src, dst, rank, row_ptr, ssrc);
    aggregate_kernel<<<N_NODES, 64, 0, stream>>>(row_ptr, ssrc,
                                                 (const __half2*)xwh, dinv, b, out);
}